// Round 10
// baseline (257.818 us; speedup 1.0000x reference)
//
#include <hip/hip_runtime.h>

typedef _Float16 half2v __attribute__((ext_vector_type(2)));
typedef _Float16 half4v __attribute__((ext_vector_type(4)));
typedef _Float16 half8v __attribute__((ext_vector_type(8)));
typedef float   float4v __attribute__((ext_vector_type(4)));

#define INC     16
#define OUTC    16
#define EFN     13
#define HIDC    32
#define EPW     128    // edges per wave
#define WPB     4      // independent waves per block (no barriers)
#define MAXSPAN 40

#define GLOBAL_AS __attribute__((address_space(1)))
#define LDS_AS    __attribute__((address_space(3)))

union H8 { half8v v; half2v h2[4]; };
union U8 { half8v v; uint4 u; };

// ---------------------------------------------------------------------------
// One-time prep (unchanged from R9): W2 fragment image, out zero, x->f16.
// ---------------------------------------------------------------------------
__global__ __launch_bounds__(256) void prep(
    const float* __restrict__ W2,
    const float* __restrict__ x,
    _Float16*    __restrict__ wsB,
    _Float16*    __restrict__ wsXh,
    float*       __restrict__ out,
    int nh)
{
    const int b = blockIdx.x;
    if (b < 32) {
        const int i = b * 256 + threadIdx.x;
        const int j = i & 7;
        const int l = (i >> 3) & 63;
        const int t = i >> 9;
        const int q = l >> 4, n = l & 15;
        const int kk = (j < 4) ? (q * 4 + j) : (16 + q * 4 + (j & 3));
        wsB[i] = (_Float16)W2[kk * 256 + t * 16 + n];
    } else {
        const int i = (b - 32) * 256 + threadIdx.x;
        if (i * 4 < nh)
            ((float4*)out)[i] = make_float4(0, 0, 0, 0);
        if (i * 8 < nh) {
            const float4 v0 = ((const float4*)x)[i * 2];
            const float4 v1 = ((const float4*)x)[i * 2 + 1];
            half8v h;
            h[0] = (_Float16)v0.x; h[1] = (_Float16)v0.y;
            h[2] = (_Float16)v0.z; h[3] = (_Float16)v0.w;
            h[4] = (_Float16)v1.x; h[5] = (_Float16)v1.y;
            h[6] = (_Float16)v1.z; h[7] = (_Float16)v1.w;
            *(half8v*)(wsXh + (size_t)i * 8) = h;
        }
    }
}

// ---------------------------------------------------------------------------
// ABLATION-INSTRUMENTED edge kernel.  MODE 0 = the passing R9 kernel (real
// output).  MODE 1 = stage-only skeleton; MODE 2 = stage+gather skeleton;
// MODE 3 = compute-only skeleton.  Skeletons write ONLY to the dummy ws
// region (keepalive tokens, rule #17) so the real output is untouched.
// Each mode is a separate dispatch -> separate rocprof row -> the 73 us
// decomposes empirically.
// ---------------------------------------------------------------------------
template<int MODE>
__global__ __launch_bounds__(256, 3) void edge_kernel(
    const _Float16* __restrict__ xh,
    const float* __restrict__ edgefeats,
    const float* __restrict__ W1,
    const float* __restrict__ b1,
    const float* __restrict__ b2,
    const int*   __restrict__ idxn,
    const int*   __restrict__ idxd,
    const float* __restrict__ degs,
    const _Float16* __restrict__ wsB,
    float*       __restrict__ out,
    float*       __restrict__ dummy,   // skeleton keepalive region
    int E)
{
    __shared__ __align__(16) float sEF[WPB][EPW * EFN];
    __shared__ __align__(16) int   sidxn[WPB][EPW];
    __shared__ float lacc[WPB][MAXSPAN * OUTC];

    const int tid  = threadIdx.x;
    const int lane = tid & 63;
    const int wid  = tid >> 6;
    const int n    = lane & 15;
    const int q    = lane >> 4;

    const long vw = (long)blockIdx.x * WPB + wid;
    const long b0 = vw * EPW;
    if (b0 >= (long)E) return;
    const long bEnd = (b0 + EPW < (long)E) ? (b0 + EPW) : (long)E;
    const bool full = (b0 + EPW <= (long)E);
    const long Em1  = (long)E - 1;
    if (MODE != 0 && !full) return;    // skeletons skip the 1 partial wave

    float* sEF_w   = sEF[wid];
    int*   sidxn_w = sidxn[wid];
    float* lacc_w  = lacc[wid];

    int nd0 = 0, nd1 = 0;
    if (MODE != 3) {
        // ---- (1) idxn for tiles 0,1 (register prefetch) ----
        const long ea = b0 + n, eb = b0 + 16 + n;
        nd0 = idxn[(ea <= Em1) ? ea : Em1];
        nd1 = idxn[(eb <= Em1) ? eb : Em1];
        __builtin_amdgcn_sched_barrier(0);

        // ---- (2) async staging: ef slab + idxn slab into PRIVATE LDS ----
        if (full) {
            const char* efsrc = (const char*)edgefeats + (size_t)b0 * (EFN * 4);
            #pragma unroll
            for (int c = 0; c < 6; ++c)
                __builtin_amdgcn_global_load_lds(
                    (const GLOBAL_AS unsigned int*)(efsrc + c * 1024 + lane * 16),
                    (LDS_AS unsigned int*)((char*)sEF_w + c * 1024), 16, 0, 0);
            if (lane < 32) {
                __builtin_amdgcn_global_load_lds(
                    (const GLOBAL_AS unsigned int*)(efsrc + 6144 + lane * 16),
                    (LDS_AS unsigned int*)((char*)sEF_w + 6144), 16, 0, 0);
                __builtin_amdgcn_global_load_lds(
                    (const GLOBAL_AS unsigned int*)((const char*)(idxn + b0) + lane * 16),
                    (LDS_AS unsigned int*)sidxn_w, 16, 0, 0);
            }
        } else {       // MODE 0 partial tail
            const long mx = (long)E * EFN - 1;
            for (int i = lane; i < EPW * EFN; i += 64) {
                long gi = b0 * EFN + i;
                if (gi > mx) gi = mx;
                sEF_w[i] = edgefeats[gi];
            }
            for (int i = lane; i < EPW; i += 64) {
                long e = b0 + i;
                if (e > Em1) e = Em1;
                sidxn_w[i] = idxn[e];
            }
        }
        __builtin_amdgcn_sched_barrier(0);
    } else {
        // MODE 3: synthesize the ef slab with cheap LDS writes (no VMEM)
        for (int i = lane; i < EPW * EFN; i += 64)
            sEF_w[i] = (float)(i & 31) * 0.01f;
    }

    int d_lo, d_hi, span;
    if (MODE == 3) { d_lo = 0; d_hi = 16; span = 16; }
    else {
        d_lo = idxd[b0];
        d_hi = idxd[bEnd - 1];
        span = d_hi - d_lo;
    }

    // ---- W2 B-fragments -> 64 regs (L2-hot image) ----
    H8 bfr[16];
    #pragma unroll
    for (int t = 0; t < 16; ++t)
        bfr[t].v = *(const half8v*)(wsB + ((size_t)(t * 64 + lane) * 8));

    // ---- zero private bins ----
    #pragma unroll
    for (int it = 0; it < MAXSPAN * OUTC / 64; ++it) lacc_w[lane + it * 64] = 0.0f;

    // ---- per-lane constants ----
    half4v a1, a2;
    float4v c1, c2;
    #pragma unroll
    for (int jj = 0; jj < 4; ++jj) {
        const int f = q * 4 + jj;
        const bool ok = (f < EFN);
        a1[jj] = ok ? (_Float16)W1[f * HIDC + n]      : (_Float16)0.f;
        a2[jj] = ok ? (_Float16)W1[f * HIDC + 16 + n] : (_Float16)0.f;
        c1[jj] = b1[q * 4 + jj];
        c2[jj] = b1[16 + q * 4 + jj];
    }
    half8v bfragB2;
    #pragma unroll
    for (int j = 0; j < 8; ++j) {
        _Float16 val = (_Float16)0.f;
        if (q < 2) val = (_Float16)b2[(q * 8 + j) * 16 + n];
        bfragB2[j] = val;
    }

    const int f0i = (q < 3) ? (q * 4) : 9;

    // ---- x pipeline prologue ----
    half8v pxa0, pxb0, pxa1, pxb1;
    if (MODE != 3) {
        pxa0 = *(const half8v*)(xh + (size_t)nd0 * INC);
        pxb0 = *(const half8v*)(xh + (size_t)nd0 * INC + 8);
        pxa1 = *(const half8v*)(xh + (size_t)nd1 * INC);
        pxb1 = *(const half8v*)(xh + (size_t)nd1 * INC + 8);
    } else {
        // synthetic, VMEM-free
        #pragma unroll
        for (int j = 0; j < 8; ++j) {
            pxa0[j] = (_Float16)((float)((lane + j) & 7) * 0.125f);
            pxb0[j] = (_Float16)((float)((lane ^ j) & 7) * 0.125f);
        }
        pxa1 = pxb0; pxb1 = pxa0;
    }
    __builtin_amdgcn_sched_barrier(0);

    // ---- drain: staging + bfr + x prologue ----
    asm volatile("s_waitcnt vmcnt(0) lgkmcnt(0)" ::: "memory");
    __builtin_amdgcn_sched_barrier(0);

    if (MODE == 1) {
        // stage-only token: keep every load class live, then exit
        float tok = (float)pxa0[0] + (float)pxb0[7] + (float)pxa1[3] + (float)pxb1[5];
        tok += sEF_w[lane] + (float)sidxn_w[lane];
        #pragma unroll
        for (int t = 0; t < 16; ++t) tok += (float)bfr[t].v[(t & 7)];
        dummy[((vw & 1023) * 64) + lane] = tok;
        return;
    }

    float ftok = 0.0f;
    unsigned utok = 0;

    // ---- fully-unrolled 8-tile loop ----
    #pragma unroll
    for (int t16 = 0; t16 < 8; ++t16) {
        const long base = b0 + (long)t16 * 16;
        const bool vM   = (MODE == 3) ? true : (base + n < (long)E);

        const half8v xA = (t16 & 1) ? pxa1 : pxa0;
        const half8v xB = (t16 & 1) ? pxb1 : pxb0;
        int4 dd;
        if (MODE != 3) {
            if (t16 < 6) {
                const int ndn = sidxn_w[(t16 + 2) * 16 + n];
                if (t16 & 1) {
                    pxa1 = *(const half8v*)(xh + (size_t)ndn * INC);
                    pxb1 = *(const half8v*)(xh + (size_t)ndn * INC + 8);
                } else {
                    pxa0 = *(const half8v*)(xh + (size_t)ndn * INC);
                    pxb0 = *(const half8v*)(xh + (size_t)ndn * INC + 8);
                }
            }
            long de = base + q * 4;
            if (de > (long)E - 4) de = (long)E - 4;
            dd = *(const int4*)(idxd + de);
            __builtin_amdgcn_sched_barrier(0);
        } else {
            const int u0 = (t16 * 2 + q) & 15;
            dd.x = u0; dd.y = u0; dd.z = u0; dd.w = u0 + (q & 1);
        }

        const float* efp = sEF_w + (size_t)(t16 * 16 + n) * EFN + f0i;
        const float e0 = efp[0], e1 = efp[1], e2 = efp[2], e3 = efp[3];

        if (MODE == 2) {
            // gather skeleton: consume loads with cheap integer adds only
            U8 ua, ub; ua.v = xA; ub.v = xB;
            utok += ua.u.x + ua.u.y + ua.u.z + ua.u.w;
            utok += ub.u.x + ub.u.y + ub.u.z + ub.u.w;
            utok += (unsigned)(dd.x + dd.y + dd.z + dd.w);
            ftok += e0 + e1 + e2 + e3;
            continue;
        }

        // ---- compute (MODE 0 / MODE 3) ----
        H8 sa, sb_;
        sa.v = xA; sb_.v = xB;
        const half2v zz = {(_Float16)0.f, (_Float16)0.f};
        half2v selh[8];
        #pragma unroll
        for (int i = 0; i < 4; ++i) {
            selh[i]     = vM ? sa.h2[i]  : zz;
            selh[4 + i] = vM ? sb_.h2[i] : zz;
        }

        half4v efB;
        if (q < 3) {
            efB[0] = (_Float16)e0; efB[1] = (_Float16)e1;
            efB[2] = (_Float16)e2; efB[3] = (_Float16)e3;
        } else {
            efB[0] = (_Float16)e3; efB[1] = (_Float16)0.f;
            efB[2] = (_Float16)0.f; efB[3] = (_Float16)0.f;
        }

        const float4v hf1 = __builtin_amdgcn_mfma_f32_16x16x16f16(a1, efB, c1, 0, 0, 0);
        const float4v hf2 = __builtin_amdgcn_mfma_f32_16x16x16f16(a2, efB, c2, 0, 0, 0);

        H8 hu;
        #pragma unroll
        for (int r = 0; r < 2; ++r) {
            half2v t1 = {(_Float16)fmaxf(hf1[2*r], 0.f), (_Float16)fmaxf(hf1[2*r+1], 0.f)};
            half2v t2 = {(_Float16)fmaxf(hf2[2*r], 0.f), (_Float16)fmaxf(hf2[2*r+1], 0.f)};
            hu.h2[r]     = t1;
            hu.h2[2 + r] = t2;
        }

        float4v acc = {0.f, 0.f, 0.f, 0.f};
        #pragma unroll
        for (int t = 0; t < 16; ++t) {
            _Float16 sv = (t & 1) ? selh[t >> 1][1] : selh[t >> 1][0];
            half2v sb = {sv, sv};
            H8 a;
            a.h2[0] = sb * hu.h2[0];
            a.h2[1] = sb * hu.h2[1];
            a.h2[2] = sb * hu.h2[2];
            a.h2[3] = sb * hu.h2[3];
            acc = __builtin_amdgcn_mfma_f32_16x16x32_f16(a.v, bfr[t].v, acc, 0, 0, 0);
        }
        {
            H8 a;
            #pragma unroll
            for (int j2 = 0; j2 < 4; ++j2) {
                a.h2[j2] = (q < 2) ? selh[q * 4 + j2] : zz;
            }
            acc = __builtin_amdgcn_mfma_f32_16x16x32_f16(a.v, bfragB2, acc, 0, 0, 0);
        }

        const int r0 = ((dd.x < d_hi) ? dd.x : d_hi) - d_lo;
        const int r1 = ((dd.y < d_hi) ? dd.y : d_hi) - d_lo;
        const int r2 = ((dd.z < d_hi) ? dd.z : d_hi) - d_lo;
        const int r3 = ((dd.w < d_hi) ? dd.w : d_hi) - d_lo;
        if (r0 == r3) {
            atomicAdd(&lacc_w[r0 * OUTC + n], acc[0] + acc[1] + acc[2] + acc[3]);
        } else {
            atomicAdd(&lacc_w[r0 * OUTC + n], acc[0]);
            atomicAdd(&lacc_w[r1 * OUTC + n], acc[1]);
            atomicAdd(&lacc_w[r2 * OUTC + n], acc[2]);
            atomicAdd(&lacc_w[r3 * OUTC + n], acc[3]);
        }
    }

    if (MODE == 2) {
        dummy[((vw & 1023) * 64) + lane] = ftok + (float)(utok & 0xffff);
        return;
    }

    asm volatile("s_waitcnt lgkmcnt(0)" ::: "memory");

    if (MODE == 3) {
        // flush bins to dummy (never to out)
        for (int i = lane; i < (span + 1) * OUTC; i += 64)
            dummy[((vw & 127) * 320) + i] = lacc_w[i];
        return;
    }

    // ---- MODE 0: real flush (R9 logic, unchanged) ----
    const bool first_starts = (b0 == 0)        || (idxd[b0 - 1] != d_lo);
    const bool last_ends    = (bEnd == (long)E) || (idxd[bEnd]   != d_hi);

    for (int i = lane; i < (span + 1) * OUTC; i += 64) {
        const int u = i >> 4;
        const int o = i & 15;
        const int v = d_lo + u;
        const float bin = lacc_w[u * OUTC + o];
        const bool starts = (u > 0)    || first_starts;
        const bool ends   = (u < span) || last_ends;
        const float dg = degs[v];
        const float val = (dg > 0.0f) ? bin / dg : 0.0f;
        if (starts && ends) {
            out[(size_t)v * OUTC + o] = val;
        } else {
            atomicAdd(&out[(size_t)v * OUTC + o], val);
        }
    }
}

// ---------------------------------------------------------------------------
extern "C" void kernel_launch(void* const* d_in, const int* in_sizes, int n_in,
                              void* d_out, int out_size, void* d_ws, size_t ws_size,
                              hipStream_t stream)
{
    const float* x         = (const float*)d_in[0];
    const float* edgefeats = (const float*)d_in[1];
    const float* W1        = (const float*)d_in[2];
    const float* b1        = (const float*)d_in[3];
    const float* W2        = (const float*)d_in[4];
    const float* b2        = (const float*)d_in[5];
    const int*   idxn      = (const int*)d_in[6];
    const int*   idxd      = (const int*)d_in[7];
    const float* degs      = (const float*)d_in[8];

    const int E = in_sizes[6];
    const int N = in_sizes[8];
    const int nvw   = (E + EPW - 1) / EPW;
    const int gridw = (nvw + WPB - 1) / WPB;
    const int nh = N * INC;

    // workspace: wsB 16 KB | wsXh N*16 f16 | dummy (skeleton tokens, 512 KB)
    _Float16* wsB  = (_Float16*)d_ws;
    _Float16* wsXh = (_Float16*)((char*)d_ws + 16384);
    size_t xh_bytes = ((size_t)nh * 2 + 255) & ~(size_t)255;
    float* dummy   = (float*)((char*)d_ws + 16384 + xh_bytes);

    const int zblocks = (nh / 4 + 255) / 256;
    prep<<<32 + zblocks, 256, 0, stream>>>(W2, x, wsB, wsXh, (float*)d_out, nh);

    // --- ablation skeletons (write only to dummy) ---
    edge_kernel<1><<<gridw, 256, 0, stream>>>(wsXh, edgefeats, W1, b1, b2,
                                              idxn, idxd, degs, wsB,
                                              (float*)d_out, dummy, E);
    edge_kernel<2><<<gridw, 256, 0, stream>>>(wsXh, edgefeats, W1, b1, b2,
                                              idxn, idxd, degs, wsB,
                                              (float*)d_out, dummy, E);
    edge_kernel<3><<<gridw, 256, 0, stream>>>(wsXh, edgefeats, W1, b1, b2,
                                              idxn, idxd, degs, wsB,
                                              (float*)d_out, dummy, E);

    // --- real kernel (R9, produces the output) ---
    edge_kernel<0><<<gridw, 256, 0, stream>>>(wsXh, edgefeats, W1, b1, b2,
                                              idxn, idxd, degs, wsB,
                                              (float*)d_out, dummy, E);
}

// Round 11
// 170.062 us; speedup vs baseline: 1.5160x; 1.5160x over previous
//
#include <hip/hip_runtime.h>

typedef _Float16 half2v __attribute__((ext_vector_type(2)));
typedef _Float16 half4v __attribute__((ext_vector_type(4)));
typedef _Float16 half8v __attribute__((ext_vector_type(8)));
typedef float   float4v __attribute__((ext_vector_type(4)));

#define INC     16
#define OUTC    16
#define EFN     13
#define HIDC    32
#define EPW     256    // edges per wave (DOUBLED: amortize per-wave overhead)
#define NT      (EPW / 16)
#define WPB     4      // independent waves per block (no barriers)
#define MAXSPAN 48     // node-range per 256-edge wave (mean ~16, sigma ~2.4)

#define GLOBAL_AS __attribute__((address_space(1)))
#define LDS_AS    __attribute__((address_space(3)))

union H8 { half8v v; half2v h2[4]; };

// ---------------------------------------------------------------------------
// One-time prep: W2 fragment image (kappa-permuted), zero out, x f32->f16.
// ---------------------------------------------------------------------------
__global__ __launch_bounds__(256) void prep(
    const float* __restrict__ W2,
    const float* __restrict__ x,
    _Float16*    __restrict__ wsB,
    _Float16*    __restrict__ wsXh,
    float*       __restrict__ out,
    int nh)
{
    const int b = blockIdx.x;
    if (b < 32) {
        const int i = b * 256 + threadIdx.x;
        const int j = i & 7;
        const int l = (i >> 3) & 63;
        const int t = i >> 9;
        const int q = l >> 4, n = l & 15;
        const int kk = (j < 4) ? (q * 4 + j) : (16 + q * 4 + (j & 3));
        wsB[i] = (_Float16)W2[kk * 256 + t * 16 + n];
    } else {
        const int i = (b - 32) * 256 + threadIdx.x;
        if (i * 4 < nh)
            ((float4*)out)[i] = make_float4(0, 0, 0, 0);
        if (i * 8 < nh) {
            const float4 v0 = ((const float4*)x)[i * 2];
            const float4 v1 = ((const float4*)x)[i * 2 + 1];
            half8v h;
            h[0] = (_Float16)v0.x; h[1] = (_Float16)v0.y;
            h[2] = (_Float16)v0.z; h[3] = (_Float16)v0.w;
            h[4] = (_Float16)v1.x; h[5] = (_Float16)v1.y;
            h[6] = (_Float16)v1.z; h[7] = (_Float16)v1.w;
            *(half8v*)(wsXh + (size_t)i * 8) = h;
        }
    }
}

// ---------------------------------------------------------------------------
// One tile (16 edges) of the R9-proven compute core.  PXA/PXB are the static
// pipeline slot NAMES (2-deep x prefetch, rule-#20-safe).  T16 is runtime.
// ---------------------------------------------------------------------------
#define DO_TILE(T16, PXA, PXB)                                               \
  {                                                                          \
    const long base = b0 + (long)(T16) * 16;                                 \
    const bool vM   = (base + n < (long)E);                                  \
    const half8v xA = PXA;                                                   \
    const half8v xB = PXB;                                                   \
    const int pft = (T16) + 2;                                               \
    if (pft < NT) {                                                          \
        const int ndn = sidxn_w[pft * 16 + n];                               \
        PXA = *(const half8v*)(xh + (size_t)ndn * INC);                      \
        PXB = *(const half8v*)(xh + (size_t)ndn * INC + 8);                  \
    }                                                                        \
    long de = base + q * 4;                                                  \
    if (de > (long)E - 4) de = (long)E - 4;                                  \
    const int4 dd = *(const int4*)(idxd + de);                               \
    __builtin_amdgcn_sched_barrier(0);                                       \
    const float* efp = sEF_w + (size_t)((T16) * 16 + n) * EFN + f0i;         \
    const float e0 = efp[0], e1 = efp[1], e2 = efp[2], e3 = efp[3];          \
    H8 sa, sb_;                                                              \
    sa.v = xA; sb_.v = xB;                                                   \
    const half2v zz = {(_Float16)0.f, (_Float16)0.f};                        \
    half2v selh[8];                                                          \
    _Pragma("unroll")                                                        \
    for (int i = 0; i < 4; ++i) {                                            \
        selh[i]     = vM ? sa.h2[i]  : zz;                                   \
        selh[4 + i] = vM ? sb_.h2[i] : zz;                                   \
    }                                                                        \
    half4v efB;                                                              \
    if (q < 3) {                                                             \
        efB[0] = (_Float16)e0; efB[1] = (_Float16)e1;                        \
        efB[2] = (_Float16)e2; efB[3] = (_Float16)e3;                        \
    } else {                                                                 \
        efB[0] = (_Float16)e3; efB[1] = (_Float16)0.f;                       \
        efB[2] = (_Float16)0.f; efB[3] = (_Float16)0.f;                      \
    }                                                                        \
    const float4v hf1 = __builtin_amdgcn_mfma_f32_16x16x16f16(a1, efB, c1, 0, 0, 0); \
    const float4v hf2 = __builtin_amdgcn_mfma_f32_16x16x16f16(a2, efB, c2, 0, 0, 0); \
    H8 hu;                                                                   \
    _Pragma("unroll")                                                        \
    for (int r = 0; r < 2; ++r) {                                            \
        half2v t1 = {(_Float16)fmaxf(hf1[2*r], 0.f), (_Float16)fmaxf(hf1[2*r+1], 0.f)}; \
        half2v t2 = {(_Float16)fmaxf(hf2[2*r], 0.f), (_Float16)fmaxf(hf2[2*r+1], 0.f)}; \
        hu.h2[r]     = t1;                                                   \
        hu.h2[2 + r] = t2;                                                   \
    }                                                                        \
    float4v acc = {0.f, 0.f, 0.f, 0.f};                                      \
    _Pragma("unroll")                                                        \
    for (int t = 0; t < 16; ++t) {                                           \
        _Float16 sv = (t & 1) ? selh[t >> 1][1] : selh[t >> 1][0];           \
        half2v sb = {sv, sv};                                                \
        H8 a;                                                                \
        a.h2[0] = sb * hu.h2[0];                                             \
        a.h2[1] = sb * hu.h2[1];                                             \
        a.h2[2] = sb * hu.h2[2];                                             \
        a.h2[3] = sb * hu.h2[3];                                             \
        acc = __builtin_amdgcn_mfma_f32_16x16x32_f16(a.v, bfr[t].v, acc, 0, 0, 0); \
    }                                                                        \
    {                                                                        \
        H8 a;                                                                \
        _Pragma("unroll")                                                    \
        for (int j2 = 0; j2 < 4; ++j2) {                                     \
            a.h2[j2] = (q < 2) ? selh[q * 4 + j2] : zz;                      \
        }                                                                    \
        acc = __builtin_amdgcn_mfma_f32_16x16x32_f16(a.v, bfragB2, acc, 0, 0, 0); \
    }                                                                        \
    const int r0 = ((dd.x < d_hi) ? dd.x : d_hi) - d_lo;                     \
    const int r1 = ((dd.y < d_hi) ? dd.y : d_hi) - d_lo;                     \
    const int r2 = ((dd.z < d_hi) ? dd.z : d_hi) - d_lo;                     \
    const int r3 = ((dd.w < d_hi) ? dd.w : d_hi) - d_lo;                     \
    if (r0 == r3) {                                                          \
        atomicAdd(&lacc_w[r0 * OUTC + n], acc[0] + acc[1] + acc[2] + acc[3]);\
    } else {                                                                 \
        atomicAdd(&lacc_w[r0 * OUTC + n], acc[0]);                           \
        atomicAdd(&lacc_w[r1 * OUTC + n], acc[1]);                           \
        atomicAdd(&lacc_w[r2 * OUTC + n], acc[2]);                           \
        atomicAdd(&lacc_w[r3 * OUTC + n], acc[3]);                           \
    }                                                                        \
  }

// ---------------------------------------------------------------------------
// 4-independent-wave MFMA edge kernel, 256 edges/wave, rolled 2-tile body.
// R9 structure otherwise: barrier-free, per-wave global_load_lds staging
// (13 ef chunks + 1 idxn chunk), register W2 B-fragments, 2-deep x pipeline,
// LDS bins, direct-store interior / atomicAdd boundary flush.
// ---------------------------------------------------------------------------
__global__ __launch_bounds__(256, 2) void edge_kernel(
    const _Float16* __restrict__ xh,       // (N,16) f16 (prebuilt)
    const float* __restrict__ edgefeats,   // (E,13)
    const float* __restrict__ W1,          // (13,32)
    const float* __restrict__ b1,          // (32,)
    const float* __restrict__ b2,          // (256,)
    const int*   __restrict__ idxn,        // (E,)
    const int*   __restrict__ idxd,        // (E,) sorted
    const float* __restrict__ degs,        // (N,)
    const _Float16* __restrict__ wsB,      // (8192,) prebuilt B image
    float*       __restrict__ out,         // (N,16) pre-zeroed output
    int E)
{
    __shared__ __align__(16) float sEF[WPB][EPW * EFN];   // 4 x 13312 B
    __shared__ __align__(16) int   sidxn[WPB][EPW];       // 4 x 1024 B
    __shared__ float lacc[WPB][MAXSPAN * OUTC];           // 4 x 3072 B
    // total 69632 B -> 2 blocks/CU -> 8 waves/CU

    const int tid  = threadIdx.x;
    const int lane = tid & 63;
    const int wid  = tid >> 6;
    const int n    = lane & 15;
    const int q    = lane >> 4;

    const long vw = (long)blockIdx.x * WPB + wid;   // virtual wave id
    const long b0 = vw * EPW;
    if (b0 >= (long)E) return;                      // padding wave
    const long bEnd = (b0 + EPW < (long)E) ? (b0 + EPW) : (long)E;
    const bool full = (b0 + EPW <= (long)E);
    const long Em1  = (long)E - 1;

    float* sEF_w   = sEF[wid];
    int*   sidxn_w = sidxn[wid];
    float* lacc_w  = lacc[wid];

    // ---- (1) first VMEM: idxn for tiles 0,1 (register prefetch) ----
    const long ea = b0 + n, eb = b0 + 16 + n;
    const int nd0 = idxn[(ea <= Em1) ? ea : Em1];
    const int nd1 = idxn[(eb <= Em1) ? eb : Em1];
    __builtin_amdgcn_sched_barrier(0);

    // ---- (2) async staging: ef slab (13 KB) + idxn slab (1 KB) ----
    if (full) {
        const char* efsrc = (const char*)edgefeats + (size_t)b0 * (EFN * 4);
        #pragma unroll
        for (int c = 0; c < 13; ++c)
            __builtin_amdgcn_global_load_lds(
                (const GLOBAL_AS unsigned int*)(efsrc + c * 1024 + lane * 16),
                (LDS_AS unsigned int*)((char*)sEF_w + c * 1024), 16, 0, 0);
        __builtin_amdgcn_global_load_lds(
            (const GLOBAL_AS unsigned int*)((const char*)(idxn + b0) + lane * 16),
            (LDS_AS unsigned int*)sidxn_w, 16, 0, 0);
    } else {
        const long mx = (long)E * EFN - 1;
        for (int i = lane; i < EPW * EFN; i += 64) {
            long gi = b0 * EFN + i;
            if (gi > mx) gi = mx;
            sEF_w[i] = edgefeats[gi];
        }
        for (int i = lane; i < EPW; i += 64) {
            long e = b0 + i;
            if (e > Em1) e = Em1;
            sidxn_w[i] = idxn[e];
        }
    }
    __builtin_amdgcn_sched_barrier(0);

    const int d_lo = idxd[b0];
    const int d_hi = idxd[bEnd - 1];
    const int span = d_hi - d_lo;   // < MAXSPAN by construction

    // ---- W2 B-fragments: 16 x dwordx4 from the L2-hot image ----
    H8 bfr[16];
    #pragma unroll
    for (int t = 0; t < 16; ++t)
        bfr[t].v = *(const half8v*)(wsB + ((size_t)(t * 64 + lane) * 8));

    // ---- zero private bins ----
    #pragma unroll
    for (int it = 0; it < MAXSPAN * OUTC / 64; ++it) lacc_w[lane + it * 64] = 0.0f;

    // ---- per-lane constants ----
    half4v a1, a2;
    float4v c1, c2;
    #pragma unroll
    for (int jj = 0; jj < 4; ++jj) {
        const int f = q * 4 + jj;
        const bool ok = (f < EFN);
        a1[jj] = ok ? (_Float16)W1[f * HIDC + n]      : (_Float16)0.f;
        a2[jj] = ok ? (_Float16)W1[f * HIDC + 16 + n] : (_Float16)0.f;
        c1[jj] = b1[q * 4 + jj];
        c2[jj] = b1[16 + q * 4 + jj];
    }
    half8v bfragB2;
    #pragma unroll
    for (int j = 0; j < 8; ++j) {
        _Float16 val = (_Float16)0.f;
        if (q < 2) val = (_Float16)b2[(q * 8 + j) * 16 + n];
        bfragB2[j] = val;
    }

    const int f0i = (q < 3) ? (q * 4) : 9;  // q==3: feats 9..12, use last

    // ---- x pipeline prologue (2-deep, static slot names) ----
    half8v pxa0 = *(const half8v*)(xh + (size_t)nd0 * INC);
    half8v pxb0 = *(const half8v*)(xh + (size_t)nd0 * INC + 8);
    half8v pxa1 = *(const half8v*)(xh + (size_t)nd1 * INC);
    half8v pxb1 = *(const half8v*)(xh + (size_t)nd1 * INC + 8);
    __builtin_amdgcn_sched_barrier(0);

    // ---- wave-level drain (no block barrier) ----
    asm volatile("s_waitcnt vmcnt(0) lgkmcnt(0)" ::: "memory");
    __builtin_amdgcn_sched_barrier(0);

    // ---- rolled 2-tile loop: 16 tiles, small code footprint ----
    for (int tt = 0; tt < NT; tt += 2) {
        DO_TILE(tt,     pxa0, pxb0)
        DO_TILE(tt + 1, pxa1, pxb1)
    }

    // ---- wave-level LDS drain (bins are wave-private) ----
    asm volatile("s_waitcnt lgkmcnt(0)" ::: "memory");

    // ---- flush: interior -> direct store w/ fused deg-division;
    //      boundary -> global atomicAdd of bin/deg (out pre-zeroed) ----
    const bool first_starts = (b0 == 0)        || (idxd[b0 - 1] != d_lo);
    const bool last_ends    = (bEnd == (long)E) || (idxd[bEnd]   != d_hi);

    for (int i = lane; i < (span + 1) * OUTC; i += 64) {
        const int u = i >> 4;
        const int o = i & 15;
        const int v = d_lo + u;
        const float bin = lacc_w[u * OUTC + o];
        const bool starts = (u > 0)    || first_starts;
        const bool ends   = (u < span) || last_ends;
        const float dg = degs[v];
        const float val = (dg > 0.0f) ? bin / dg : 0.0f;
        if (starts && ends) {
            out[(size_t)v * OUTC + o] = val;
        } else {
            atomicAdd(&out[(size_t)v * OUTC + o], val);
        }
    }
}

// ---------------------------------------------------------------------------
extern "C" void kernel_launch(void* const* d_in, const int* in_sizes, int n_in,
                              void* d_out, int out_size, void* d_ws, size_t ws_size,
                              hipStream_t stream)
{
    const float* x         = (const float*)d_in[0];
    const float* edgefeats = (const float*)d_in[1];
    const float* W1        = (const float*)d_in[2];
    const float* b1        = (const float*)d_in[3];
    const float* W2        = (const float*)d_in[4];
    const float* b2        = (const float*)d_in[5];
    const int*   idxn      = (const int*)d_in[6];
    const int*   idxd      = (const int*)d_in[7];
    const float* degs      = (const float*)d_in[8];

    const int E = in_sizes[6];
    const int N = in_sizes[8];
    const int nvw   = (E + EPW - 1) / EPW;          // virtual waves
    const int gridw = (nvw + WPB - 1) / WPB;        // blocks of 4 waves
    const int nh = N * INC;

    // workspace layout: wsB (16 KB) | wsXh (N*16 f16)
    _Float16* wsB  = (_Float16*)d_ws;
    _Float16* wsXh = (_Float16*)((char*)d_ws + 16384);

    const int zblocks = (nh / 4 + 255) / 256;
    prep<<<32 + zblocks, 256, 0, stream>>>(W2, x, wsB, wsXh, (float*)d_out, nh);

    edge_kernel<<<gridw, 256, 0, stream>>>(wsXh, edgefeats, W1, b1, b2,
                                           idxn, idxd, degs, wsB,
                                           (float*)d_out, E);
}